// Round 7
// baseline (320.269 us; speedup 1.0000x reference)
//
#include <hip/hip_runtime.h>
#include <stdint.h>

#define N_ANCH 4096
#define NCLS 8
#define CN (N_ANCH * NCLS)
#define SCORE_TH 0.5f
#define IOU_TH 0.5f
#define KSEL 11
#define MAX_DET 100
#define CAND_CAP 4096
#define TILE 128
#define TPC (N_ANCH / TILE)          // 32 i/j tiles per class (worst case)
#define NTRI (TPC * (TPC + 1) / 2)   // 528 triangular tiles per class

__device__ __forceinline__ float iou_f(float4 a, float areaA, float4 b, float areaB) {
    float x1 = fmaxf(a.x, b.x);
    float y1 = fmaxf(a.y, b.y);
    float x2 = fminf(a.z, b.z);
    float y2 = fminf(a.w, b.w);
    float wid = x2 - x1 + 1.0f;
    float hei = y2 - y1 + 1.0f;
    float inter = wid * hei;
    float den = areaA + areaB - inter;
    float ov = (den == 0.0f) ? 0.0f : (inter / den);
    if (wid <= 0.0f || hei <= 0.0f) ov = 0.0f;
    return ov;
}

// K1 (128 blocks x 256): coalesced input reads, scatter-write transposed SoA +
// areas, init surv/minRank/done.
__global__ void __launch_bounds__(256) k_prep(const float* __restrict__ boxes,
                                              const float* __restrict__ cls,
                                              const float* __restrict__ conf,
                                              float4* boxesT, float* areaT,
                                              float* scoresT, float* confT,
                                              int* surv, int* minRank, int* done) {
    int t = blockIdx.x * 256 + threadIdx.x;
    int n = t >> 3;  // anchor
    int c = t & 7;   // class
    int p = (c << 12) + n;
    scoresT[p] = cls[t];
    confT[p] = conf[t];
    float4 b = reinterpret_cast<const float4*>(boxes)[t];
    boxesT[p] = b;
    areaT[p] = (b.z - b.x + 1.0f) * (b.w - b.y + 1.0f);
    surv[t] = 0;
    minRank[t] = 0x7FFFFFFF;
    if (t < 8) done[t] = 0;
}

// K2 (8 blocks x 1024): single-pass per-class compaction; coalesced float4
// score reads; emits rank-compacted vBox/vArea/vConf (gathers hit L2).
__global__ void __launch_bounds__(1024) k_validlist(const float* __restrict__ scoresT,
                                                    const float4* __restrict__ boxesT,
                                                    const float* __restrict__ areaT,
                                                    const float* __restrict__ confT,
                                                    int* validList, float4* vBox,
                                                    float* vArea, float* vConf, int* mVal) {
    int c = blockIdx.x;
    int tid = threadIdx.x;
    int lane = tid & 63, wid = tid >> 6;
    __shared__ int wsum[16];
    int cbase = c << 12;
    float4 sc = reinterpret_cast<const float4*>(scoresT + cbase)[tid];
    int f0 = sc.x > SCORE_TH, f1 = sc.y > SCORE_TH, f2 = sc.z > SCORE_TH, f3 = sc.w > SCORE_TH;
    int f = f0 + f1 + f2 + f3;
    int inc = f;
    for (int off = 1; off < 64; off <<= 1) {
        int o = __shfl_up(inc, off);
        if (lane >= off) inc += o;
    }
    if (lane == 63) wsum[wid] = inc;
    __syncthreads();
    int wbase = 0;
    for (int i = 0; i < wid; i++) wbase += wsum[i];
    int pos = wbase + inc - f;  // exclusive prefix
    int n0 = tid * 4;
    int fl[4] = {f0, f1, f2, f3};
    #pragma unroll
    for (int d = 0; d < 4; d++) {
        if (fl[d]) {
            int n = n0 + d;
            validList[cbase + pos] = n;
            vBox[cbase + pos] = boxesT[cbase + n];
            vArea[cbase + pos] = areaT[cbase + n];
            vConf[cbase + pos] = confT[cbase + n];
            pos++;
        }
    }
    if (tid == 1023) mVal[c] = wbase + inc;
}

// K3: triangular tiled rep-matrix + per-class LAST-BLOCK finalize (repA + surv
// + classCnt). All NTRI blocks of a class hit the done counter; the last one
// (device-scope acq_rel) finalizes the class, reading minRank with
// agent-scope atomic loads (cross-XCD safety).
__global__ void __launch_bounds__(128) k_repmat(const float4* __restrict__ vBox,
                                                const float* __restrict__ vArea,
                                                const float* __restrict__ vConf,
                                                const int* __restrict__ validList,
                                                const int* __restrict__ mVal,
                                                int* minRank, int* done,
                                                int* rep, int* surv, int* classCnt) {
    int bid = blockIdx.x;
    int c = bid / NTRI;
    int t = bid - c * NTRI;
    int ci = (int)((sqrtf(8.0f * (float)t + 1.0f) - 1.0f) * 0.5f);
    while ((ci + 1) * (ci + 2) / 2 <= t) ci++;
    while (ci * (ci + 1) / 2 > t) ci--;
    int cj = t - ci * (ci + 1) / 2;
    int mc = mVal[c];
    int ib = ci * TILE, jb = cj * TILE;
    int tid = threadIdx.x;
    int cbase = c << 12;
    __shared__ float4 sB[TILE];
    __shared__ float sA[TILE];
    __shared__ int lastS;
    bool activeTile = (ib < mc) && (jb < mc);
    if (activeTile) {
        if (jb + tid < mc) {
            sB[tid] = vBox[cbase + jb + tid];
            sA[tid] = vArea[cbase + jb + tid];
        }
        __syncthreads();
        int i = ib + tid;
        if (i < mc) {
            float4 bk = vBox[cbase + i];
            float ak = vArea[cbase + i];
            int limit = min(TILE, mc - jb);
            if (ci == cj) limit = min(limit, i - jb);  // strictly below diagonal
            int lmin = 0x7FFFFFFF;
            #pragma unroll 4
            for (int r = 0; r < limit; r++) {
                float ov = iou_f(bk, ak, sB[r], sA[r]);
                if (ov > IOU_TH && r < lmin) lmin = r;
            }
            if (lmin != 0x7FFFFFFF) atomicMin(&minRank[cbase + i], jb + lmin);
        }
    }
    // ---- completion counter (every block of this class, active or not) ----
    __syncthreads();
    __threadfence();
    if (tid == 0) {
        int prev = __hip_atomic_fetch_add(&done[c], 1, __ATOMIC_ACQ_REL,
                                          __HIP_MEMORY_SCOPE_AGENT);
        lastS = (prev == NTRI - 1) ? 1 : 0;
    }
    __syncthreads();
    if (!lastS) return;
    __threadfence();
    // ---- finalize class c: rep + surv ----
    for (int i = tid; i < mc; i += 128) {
        int k = validList[cbase + i];
        int mr = __hip_atomic_load(&minRank[cbase + i], __ATOMIC_RELAXED,
                                   __HIP_MEMORY_SCOPE_AGENT);
        if (mr > i) mr = i;  // self
        int j = validList[cbase + mr];
        rep[cbase + k] = j;
        if (mr < i) {
            float ov = iou_f(vBox[cbase + i], vArea[cbase + i],
                             vBox[cbase + mr], vArea[cbase + mr]);
            float bcv = (1.0f - ov) * vConf[cbase + i];
            if (bcv != 0.0f) surv[cbase + j] = 1;  // single-block scatter now
        }
    }
    __syncthreads();
    // ---- survivor count for this class ----
    int cnt = 0;
    for (int n = tid; n < N_ANCH; n += 128) cnt += (surv[cbase + n] != 0);
    for (int off = 32; off > 0; off >>= 1) cnt += __shfl_down(cnt, off);
    __shared__ int wred[2];
    if ((tid & 63) == 0) wred[tid >> 6] = cnt;
    __syncthreads();
    if (tid == 0) classCnt[c] = wred[0] + wred[1];
}

// K4 (101 blocks x 1024): block 0 = top-100 survivor scores (LDS histogram
// threshold + gather + bitonic). Blocks 1..100 = slot s: locate s-th survivor
// (classCnt prefix + one-pass in-class scan), then cluster gather/average.
__global__ void __launch_bounds__(1024) k_final(const float4* __restrict__ boxesT,
                                                const float* __restrict__ areaT,
                                                const float* __restrict__ confT,
                                                const float* __restrict__ scoresT,
                                                const float* __restrict__ poses,
                                                const int* __restrict__ rep,
                                                const int* __restrict__ surv,
                                                const int* __restrict__ classCnt,
                                                float* out) {
    int bid = blockIdx.x, tid = threadIdx.x;
    int lane = tid & 63, w = tid >> 6;
    __shared__ int coff[9];
    __shared__ int hist[1024];
    __shared__ int sfx[256];
    __shared__ float sc[CAND_CAP];
    __shared__ unsigned long long keyArr[4096];
    __shared__ int wsum[16];
    __shared__ unsigned long long redK[16];
    __shared__ int thrB, ccS, rS, nmS;
    __shared__ unsigned long long bestS;

    if (tid < 8) coff[tid + 1] = classCnt[tid];
    if (tid == 0) coff[0] = 0;
    __syncthreads();
    if (tid == 0) for (int i = 0; i < 8; i++) coff[i + 1] += coff[i];
    __syncthreads();
    int count = coff[8];

    if (bid == 0) {
        // ---- top-100 scores ----
        hist[tid] = 0;
        if (tid == 0) { thrB = 0; ccS = 0; }
        __syncthreads();
        for (int p = tid; p < CN; p += 1024) {
            if (surv[p]) {
                unsigned bits = __float_as_uint(scoresT[p]);
                int bb = (int)((bits - 0x3F000000u) >> 13);
                int bkt = bb < 0 ? 0 : (bb > 1023 ? 1023 : bb);
                atomicAdd(&hist[bkt], 1);
            }
        }
        __syncthreads();
        int target = count < MAX_DET ? count : MAX_DET;
        if (tid < 256)
            sfx[tid] = hist[4 * tid] + hist[4 * tid + 1] + hist[4 * tid + 2] + hist[4 * tid + 3];
        __syncthreads();
        if (tid == 0) {
            int run = 0;
            for (int i = 255; i >= 0; i--) { int v = sfx[i]; sfx[i] = run; run += v; }
        }
        __syncthreads();
        if (tid < 256) {
            int S = sfx[tid];
            int found = -1;
            for (int b = 4 * tid + 3; b >= 4 * tid; b--) {
                S += hist[b];
                if (found < 0 && S >= target) found = b;
            }
            if (found >= 0) atomicMax(&thrB, found);
        }
        __syncthreads();
        int t0 = thrB;
        for (int p = tid; p < CN; p += 1024) {
            if (surv[p]) {
                float v = scoresT[p];
                unsigned bits = __float_as_uint(v);
                int bb = (int)((bits - 0x3F000000u) >> 13);
                int bkt = bb < 0 ? 0 : (bb > 1023 ? 1023 : bb);
                if (bkt >= t0) {
                    int id = atomicAdd(&ccS, 1);
                    if (id < CAND_CAP) sc[id] = -v;
                }
            }
        }
        __syncthreads();
        int cc = ccS; if (cc > CAND_CAP) cc = CAND_CAP;
        int n = 128; while (n < cc) n <<= 1;
        for (int i = tid; i < n; i += 1024) if (i >= cc) sc[i] = 1e38f;
        __syncthreads();
        for (int kk = 2; kk <= n; kk <<= 1) {
            for (int jj = kk >> 1; jj > 0; jj >>= 1) {
                for (int i = tid; i < n; i += 1024) {
                    int ixj = i ^ jj;
                    if (ixj > i) {
                        float a = sc[i], b2 = sc[ixj];
                        bool up = ((i & kk) == 0);
                        if (up ? (a > b2) : (a < b2)) { sc[i] = b2; sc[ixj] = a; }
                    }
                }
                __syncthreads();
            }
        }
        if (tid < MAX_DET) out[tid] = (tid < count) ? -sc[tid] : -1.0f;
        return;
    }

    int s = bid - 1;
    if (s >= count) {
        if (tid == 0) { out[100 + s] = -1.0f; out[1400 + s] = -1.0f; }
        if (tid < 12) out[200 + s * 12 + tid] = -1.0f;
        if (tid >= 16 && tid < 20) out[1500 + s * 4 + (tid - 16)] = -1.0f;
        return;
    }
    // ---- locate the s-th survivor: class, then in-class rank scan ----
    int c = 0;
    while (coff[c + 1] <= s) c++;
    int l = s - coff[c];
    int cbase = c << 12;
    {
        int4 sv = reinterpret_cast<const int4*>(surv + cbase)[tid];
        int f0 = sv.x != 0, f1 = sv.y != 0, f2 = sv.z != 0, f3 = sv.w != 0;
        int f = f0 + f1 + f2 + f3;
        int inc = f;
        for (int off = 1; off < 64; off <<= 1) {
            int o = __shfl_up(inc, off);
            if (lane >= off) inc += o;
        }
        if (lane == 63) wsum[w] = inc;
        if (tid == 0) nmS = 0;
        __syncthreads();
        int base = 0;
        for (int i = 0; i < w; i++) base += wsum[i];
        int e = base + inc - f;  // exclusive prefix
        if (l >= e && l < e + f) {
            int need = l - e;
            int fl[4] = {f0, f1, f2, f3};
            #pragma unroll
            for (int d = 0; d < 4; d++) {
                if (fl[d]) { if (need == 0) rS = 4 * tid + d; need--; }
            }
        }
        __syncthreads();
    }
    int r = rS;
    // ---- gather cluster members ----
    float4 br = boxesT[cbase + r];
    float ar = areaT[cbase + r];
    for (int k = tid; k < N_ANCH; k += 1024) {
        int rp = rep[cbase + k];  // unwritten entries hold poison (negative)
        if (rp == r && k != r) {
            float ov = iou_f(br, ar, boxesT[cbase + k], areaT[cbase + k]);
            float bcv = (1.0f - ov) * confT[cbase + k];
            if (bcv != 0.0f) {
                int id = atomicAdd(&nmS, 1);
                if (id < 4096)
                    keyArr[id] = ((unsigned long long)__float_as_uint(bcv) << 32) | (unsigned)k;
            }
        }
    }
    __syncthreads();
    int nm = nmS;
    int dn = nm < KSEL ? nm : KSEL;
    __shared__ int kselS[KSEL];
    if (nm > KSEL) {
        unsigned long long lastBest = ~0ull;
        for (int j = 0; j < KSEL; j++) {
            unsigned long long bk = ~0ull;
            for (int i = tid; i < nm; i += 1024) {
                unsigned long long v = keyArr[i];
                if (v == lastBest) { keyArr[i] = ~0ull; v = ~0ull; }
                if (v < bk) bk = v;
            }
            for (int off = 32; off > 0; off >>= 1) {
                unsigned long long o = __shfl_down(bk, off);
                if (o < bk) bk = o;
            }
            if (lane == 0) redK[w] = bk;
            __syncthreads();
            if (tid == 0) {
                unsigned long long B = redK[0];
                for (int q2 = 1; q2 < 16; q2++) if (redK[q2] < B) B = redK[q2];
                bestS = B;
                kselS[j] = (int)(B & 0xFFFFFFFFull);
            }
            __syncthreads();
            lastBest = bestS;
        }
    } else if (tid < dn) {
        kselS[tid] = (int)(keyArr[tid] & 0xFFFFFFFFull);
    }
    __syncthreads();
    float fdn = (float)(dn > 0 ? dn : 1);
    if (tid < 12) {
        float ssum = 0.0f;
        for (int j = 0; j < dn; j++) ssum += poses[(kselS[j] * 8 + c) * 12 + tid];
        out[200 + s * 12 + tid] = ssum / fdn;
    } else if (tid < 16) {
        int d = tid - 12;
        float ssum = 0.0f;
        for (int j = 0; j < dn; j++) {
            const float* bb = (const float*)&boxesT[cbase + kselS[j]];
            ssum += bb[d];
        }
        out[1500 + s * 4 + d] = ssum / fdn;
    } else if (tid == 16) {
        out[100 + s] = (float)c;
    } else if (tid == 17) {
        out[1400 + s] = (float)r;
    }
}

extern "C" void kernel_launch(void* const* d_in, const int* in_sizes, int n_in,
                              void* d_out, int out_size, void* d_ws, size_t ws_size,
                              hipStream_t stream) {
    const float* boxes = (const float*)d_in[1];
    const float* cls   = (const float*)d_in[2];
    const float* poses = (const float*)d_in[3];
    const float* conf  = (const float*)d_in[4];
    float* out = (float*)d_out;

    char* ws = (char*)d_ws;
    size_t off = 0;
    auto alloc = [&](size_t bytes) {
        void* p = ws + off;
        off += (bytes + 255) & ~(size_t)255;
        return p;
    };
    float4* boxesT   = (float4*)alloc(CN * sizeof(float4));
    float*  areaT    = (float*)alloc(CN * sizeof(float));
    float*  scoresT  = (float*)alloc(CN * sizeof(float));
    float*  confT    = (float*)alloc(CN * sizeof(float));
    int*    validList= (int*)alloc(CN * sizeof(int));
    float4* vBox     = (float4*)alloc(CN * sizeof(float4));
    float*  vArea    = (float*)alloc(CN * sizeof(float));
    float*  vConf    = (float*)alloc(CN * sizeof(float));
    int*    mVal     = (int*)alloc(64);
    int*    rep      = (int*)alloc(CN * sizeof(int));
    int*    surv     = (int*)alloc(CN * sizeof(int));
    int*    minRank  = (int*)alloc(CN * sizeof(int));
    int*    done     = (int*)alloc(64);
    int*    classCnt = (int*)alloc(64);

    k_prep<<<CN / 256, 256, 0, stream>>>(boxes, cls, conf, boxesT, areaT, scoresT, confT,
                                         surv, minRank, done);
    k_validlist<<<NCLS, 1024, 0, stream>>>(scoresT, boxesT, areaT, confT,
                                           validList, vBox, vArea, vConf, mVal);
    k_repmat<<<NCLS * NTRI, 128, 0, stream>>>(vBox, vArea, vConf, validList, mVal,
                                              minRank, done, rep, surv, classCnt);
    k_final<<<1 + MAX_DET, 1024, 0, stream>>>(boxesT, areaT, confT, scoresT, poses,
                                              rep, surv, classCnt, out);
}

// Round 8
// 180.310 us; speedup vs baseline: 1.7762x; 1.7762x over previous
//
#include <hip/hip_runtime.h>
#include <stdint.h>

#define N_ANCH 4096
#define NCLS 8
#define CN (N_ANCH * NCLS)
#define SCORE_TH 0.5f
#define IOU_TH 0.5f
#define KSEL 11
#define MAX_DET 100
#define CAND_CAP 4096
#define TILE 128
#define TPC (N_ANCH / TILE)          // 32 i/j tiles per class (worst case)
#define NTRI (TPC * (TPC + 1) / 2)   // 528 triangular tiles per class

__device__ __forceinline__ float iou_f(float4 a, float areaA, float4 b, float areaB) {
    float x1 = fmaxf(a.x, b.x);
    float y1 = fmaxf(a.y, b.y);
    float x2 = fminf(a.z, b.z);
    float y2 = fminf(a.w, b.w);
    float wid = x2 - x1 + 1.0f;
    float hei = y2 - y1 + 1.0f;
    float inter = wid * hei;
    float den = areaA + areaB - inter;
    float ov = (den == 0.0f) ? 0.0f : (inter / den);
    if (wid <= 0.0f || hei <= 0.0f) ov = 0.0f;
    return ov;
}

// K1 (128 blocks x 256): coalesced input reads, scatter-write transposed SoA +
// areas, init surv/minRank/classCnt. (NO device-scope fences anywhere — round-7
// lesson: per-block __threadfence costs ~50ns serialized across the grid.)
__global__ void __launch_bounds__(256) k_prep(const float* __restrict__ boxes,
                                              const float* __restrict__ cls,
                                              const float* __restrict__ conf,
                                              float4* boxesT, float* areaT,
                                              float* scoresT, float* confT,
                                              int* surv, int* minRank, int* classCnt) {
    int t = blockIdx.x * 256 + threadIdx.x;
    int n = t >> 3;  // anchor
    int c = t & 7;   // class
    int p = (c << 12) + n;
    scoresT[p] = cls[t];
    confT[p] = conf[t];
    float4 b = reinterpret_cast<const float4*>(boxes)[t];
    boxesT[p] = b;
    areaT[p] = (b.z - b.x + 1.0f) * (b.w - b.y + 1.0f);
    surv[t] = 0;
    minRank[t] = 0x7FFFFFFF;
    if (t < 8) classCnt[t] = 0;
}

// K2 (8 blocks x 1024): single-pass per-class compaction; coalesced float4
// score reads; emits rank-compacted vBox/vArea/vConf (gathers hit L2).
__global__ void __launch_bounds__(1024) k_validlist(const float* __restrict__ scoresT,
                                                    const float4* __restrict__ boxesT,
                                                    const float* __restrict__ areaT,
                                                    const float* __restrict__ confT,
                                                    int* validList, float4* vBox,
                                                    float* vArea, float* vConf, int* mVal) {
    int c = blockIdx.x;
    int tid = threadIdx.x;
    int lane = tid & 63, wid = tid >> 6;
    __shared__ int wsum[16];
    int cbase = c << 12;
    float4 sc = reinterpret_cast<const float4*>(scoresT + cbase)[tid];
    int f0 = sc.x > SCORE_TH, f1 = sc.y > SCORE_TH, f2 = sc.z > SCORE_TH, f3 = sc.w > SCORE_TH;
    int f = f0 + f1 + f2 + f3;
    int inc = f;
    for (int off = 1; off < 64; off <<= 1) {
        int o = __shfl_up(inc, off);
        if (lane >= off) inc += o;
    }
    if (lane == 63) wsum[wid] = inc;
    __syncthreads();
    int wbase = 0;
    for (int i = 0; i < wid; i++) wbase += wsum[i];
    int pos = wbase + inc - f;  // exclusive prefix
    int n0 = tid * 4;
    int fl[4] = {f0, f1, f2, f3};
    #pragma unroll
    for (int d = 0; d < 4; d++) {
        if (fl[d]) {
            int n = n0 + d;
            validList[cbase + pos] = n;
            vBox[cbase + pos] = boxesT[cbase + n];
            vArea[cbase + pos] = areaT[cbase + n];
            vConf[cbase + pos] = confT[cbase + n];
            pos++;
        }
    }
    if (tid == 1023) mVal[c] = wbase + inc;
}

// K3: triangular tiled rep-matrix over rank-compacted boxes (round-6 version,
// fence-free). Block = (class, i-tile, j-tile<=i-tile), 128 threads, j-tile in
// LDS, no-break min scan, rare atomicMin.
__global__ void __launch_bounds__(128) k_repmat(const float4* __restrict__ vBox,
                                                const float* __restrict__ vArea,
                                                const int* __restrict__ mVal,
                                                int* minRank) {
    int bid = blockIdx.x;
    int c = bid / NTRI;
    int t = bid - c * NTRI;
    int ci = (int)((sqrtf(8.0f * (float)t + 1.0f) - 1.0f) * 0.5f);
    while ((ci + 1) * (ci + 2) / 2 <= t) ci++;
    while (ci * (ci + 1) / 2 > t) ci--;
    int cj = t - ci * (ci + 1) / 2;
    int mc = mVal[c];
    int ib = ci * TILE, jb = cj * TILE;
    if (ib >= mc || jb >= mc) return;
    int tid = threadIdx.x;
    int cbase = c << 12;
    __shared__ float4 sB[TILE];
    __shared__ float sA[TILE];
    if (jb + tid < mc) {
        sB[tid] = vBox[cbase + jb + tid];
        sA[tid] = vArea[cbase + jb + tid];
    }
    __syncthreads();
    int i = ib + tid;
    if (i >= mc) return;
    float4 bk = vBox[cbase + i];
    float ak = vArea[cbase + i];
    int limit = min(TILE, mc - jb);
    if (ci == cj) limit = min(limit, i - jb);  // strictly below diagonal
    int lmin = 0x7FFFFFFF;
    #pragma unroll 4
    for (int r = 0; r < limit; r++) {
        float ov = iou_f(bk, ak, sB[r], sA[r]);
        if (ov > IOU_TH && r < lmin) lmin = r;
    }
    if (lmin != 0x7FFFFFFF) atomicMin(&minRank[cbase + i], jb + lmin);
}

// K4: finalize rep + surv from minRank (coalesced over ranks) + distinct-
// survivor count per class via atomicExch.
__global__ void __launch_bounds__(256) k_repA(const float4* __restrict__ vBox,
                                              const float* __restrict__ vArea,
                                              const float* __restrict__ vConf,
                                              const int* __restrict__ validList,
                                              const int* __restrict__ mVal,
                                              const int* __restrict__ minRank,
                                              int* rep, int* surv, int* classCnt) {
    int t = blockIdx.x * 256 + threadIdx.x;
    int c = t >> 12;
    int i = t & (N_ANCH - 1);
    int mc = mVal[c];
    if (i >= mc) return;
    int cbase = c << 12;
    int k = validList[cbase + i];
    int mr = minRank[cbase + i];
    if (mr > i) mr = i;  // self
    int j = validList[cbase + mr];
    rep[cbase + k] = j;
    if (mr < i) {
        float ov = iou_f(vBox[cbase + i], vArea[cbase + i], vBox[cbase + mr], vArea[cbase + mr]);
        float bcv = (1.0f - ov) * vConf[cbase + i];
        if (bcv != 0.0f) {
            int old = atomicExch(&surv[cbase + j], 1);
            if (old == 0) atomicAdd(&classCnt[c], 1);
        }
    }
}

// K5 (101 blocks x 1024): block 0 = top-100 survivor scores (LDS histogram
// threshold + gather + bitonic). Blocks 1..100 = slot s: locate s-th survivor
// (classCnt prefix + in-class prefix scan), then cluster gather/average.
__global__ void __launch_bounds__(1024) k_final(const float4* __restrict__ boxesT,
                                                const float* __restrict__ areaT,
                                                const float* __restrict__ confT,
                                                const float* __restrict__ scoresT,
                                                const float* __restrict__ poses,
                                                const int* __restrict__ rep,
                                                const int* __restrict__ surv,
                                                const int* __restrict__ classCnt,
                                                float* out) {
    int bid = blockIdx.x, tid = threadIdx.x;
    int lane = tid & 63, w = tid >> 6;
    __shared__ int coff[9];
    __shared__ int hist[1024];
    __shared__ int sfx[256];
    __shared__ float sc[CAND_CAP];
    __shared__ unsigned long long keyArr[4096];
    __shared__ int wsum[16];
    __shared__ unsigned long long redK[16];
    __shared__ int thrB, ccS, rS, nmS;
    __shared__ unsigned long long bestS;

    if (tid < 8) coff[tid + 1] = classCnt[tid];
    if (tid == 0) coff[0] = 0;
    __syncthreads();
    if (tid == 0) for (int i = 0; i < 8; i++) coff[i + 1] += coff[i];
    __syncthreads();
    int count = coff[8];

    if (bid == 0) {
        // ---- top-100 scores ----
        hist[tid] = 0;
        if (tid == 0) { thrB = 0; ccS = 0; }
        __syncthreads();
        for (int p = tid; p < CN; p += 1024) {
            if (surv[p]) {
                unsigned bits = __float_as_uint(scoresT[p]);
                int bb = (int)((bits - 0x3F000000u) >> 13);
                int bkt = bb < 0 ? 0 : (bb > 1023 ? 1023 : bb);
                atomicAdd(&hist[bkt], 1);
            }
        }
        __syncthreads();
        int target = count < MAX_DET ? count : MAX_DET;
        if (tid < 256)
            sfx[tid] = hist[4 * tid] + hist[4 * tid + 1] + hist[4 * tid + 2] + hist[4 * tid + 3];
        __syncthreads();
        if (tid == 0) {
            int run = 0;
            for (int i = 255; i >= 0; i--) { int v = sfx[i]; sfx[i] = run; run += v; }
        }
        __syncthreads();
        if (tid < 256) {
            int S = sfx[tid];
            int found = -1;
            for (int b = 4 * tid + 3; b >= 4 * tid; b--) {
                S += hist[b];
                if (found < 0 && S >= target) found = b;
            }
            if (found >= 0) atomicMax(&thrB, found);
        }
        __syncthreads();
        int t0 = thrB;
        for (int p = tid; p < CN; p += 1024) {
            if (surv[p]) {
                float v = scoresT[p];
                unsigned bits = __float_as_uint(v);
                int bb = (int)((bits - 0x3F000000u) >> 13);
                int bkt = bb < 0 ? 0 : (bb > 1023 ? 1023 : bb);
                if (bkt >= t0) {
                    int id = atomicAdd(&ccS, 1);
                    if (id < CAND_CAP) sc[id] = -v;
                }
            }
        }
        __syncthreads();
        int cc = ccS; if (cc > CAND_CAP) cc = CAND_CAP;
        int n = 128; while (n < cc) n <<= 1;
        for (int i = tid; i < n; i += 1024) if (i >= cc) sc[i] = 1e38f;
        __syncthreads();
        for (int kk = 2; kk <= n; kk <<= 1) {
            for (int jj = kk >> 1; jj > 0; jj >>= 1) {
                for (int i = tid; i < n; i += 1024) {
                    int ixj = i ^ jj;
                    if (ixj > i) {
                        float a = sc[i], b2 = sc[ixj];
                        bool up = ((i & kk) == 0);
                        if (up ? (a > b2) : (a < b2)) { sc[i] = b2; sc[ixj] = a; }
                    }
                }
                __syncthreads();
            }
        }
        if (tid < MAX_DET) out[tid] = (tid < count) ? -sc[tid] : -1.0f;
        return;
    }

    int s = bid - 1;
    if (s >= count) {
        if (tid == 0) { out[100 + s] = -1.0f; out[1400 + s] = -1.0f; }
        if (tid < 12) out[200 + s * 12 + tid] = -1.0f;
        if (tid >= 16 && tid < 20) out[1500 + s * 4 + (tid - 16)] = -1.0f;
        return;
    }
    // ---- locate the s-th survivor: class, then in-class rank scan ----
    int c = 0;
    while (coff[c + 1] <= s) c++;
    int l = s - coff[c];
    int cbase = c << 12;
    {
        int4 sv = reinterpret_cast<const int4*>(surv + cbase)[tid];
        int f0 = sv.x != 0, f1 = sv.y != 0, f2 = sv.z != 0, f3 = sv.w != 0;
        int f = f0 + f1 + f2 + f3;
        int inc = f;
        for (int off = 1; off < 64; off <<= 1) {
            int o = __shfl_up(inc, off);
            if (lane >= off) inc += o;
        }
        if (lane == 63) wsum[w] = inc;
        if (tid == 0) nmS = 0;
        __syncthreads();
        int base = 0;
        for (int i = 0; i < w; i++) base += wsum[i];
        int e = base + inc - f;  // exclusive prefix
        if (l >= e && l < e + f) {
            int need = l - e;
            int fl[4] = {f0, f1, f2, f3};
            #pragma unroll
            for (int d = 0; d < 4; d++) {
                if (fl[d]) { if (need == 0) rS = 4 * tid + d; need--; }
            }
        }
        __syncthreads();
    }
    int r = rS;
    // ---- gather cluster members ----
    float4 br = boxesT[cbase + r];
    float ar = areaT[cbase + r];
    for (int k = tid; k < N_ANCH; k += 1024) {
        int rp = rep[cbase + k];  // unwritten entries hold poison -> no match
        if (rp == r && k != r) {
            float ov = iou_f(br, ar, boxesT[cbase + k], areaT[cbase + k]);
            float bcv = (1.0f - ov) * confT[cbase + k];
            if (bcv != 0.0f) {
                int id = atomicAdd(&nmS, 1);
                if (id < 4096)
                    keyArr[id] = ((unsigned long long)__float_as_uint(bcv) << 32) | (unsigned)k;
            }
        }
    }
    __syncthreads();
    int nm = nmS;
    int dn = nm < KSEL ? nm : KSEL;
    __shared__ int kselS[KSEL];
    if (nm > KSEL) {
        unsigned long long lastBest = ~0ull;
        for (int j = 0; j < KSEL; j++) {
            unsigned long long bk = ~0ull;
            for (int i = tid; i < nm; i += 1024) {
                unsigned long long v = keyArr[i];
                if (v == lastBest) { keyArr[i] = ~0ull; v = ~0ull; }
                if (v < bk) bk = v;
            }
            for (int off = 32; off > 0; off >>= 1) {
                unsigned long long o = __shfl_down(bk, off);
                if (o < bk) bk = o;
            }
            if (lane == 0) redK[w] = bk;
            __syncthreads();
            if (tid == 0) {
                unsigned long long B = redK[0];
                for (int q2 = 1; q2 < 16; q2++) if (redK[q2] < B) B = redK[q2];
                bestS = B;
                kselS[j] = (int)(B & 0xFFFFFFFFull);
            }
            __syncthreads();
            lastBest = bestS;
        }
    } else if (tid < dn) {
        kselS[tid] = (int)(keyArr[tid] & 0xFFFFFFFFull);
    }
    __syncthreads();
    float fdn = (float)(dn > 0 ? dn : 1);
    if (tid < 12) {
        float ssum = 0.0f;
        for (int j = 0; j < dn; j++) ssum += poses[(kselS[j] * 8 + c) * 12 + tid];
        out[200 + s * 12 + tid] = ssum / fdn;
    } else if (tid < 16) {
        int d = tid - 12;
        float ssum = 0.0f;
        for (int j = 0; j < dn; j++) {
            const float* bb = (const float*)&boxesT[cbase + kselS[j]];
            ssum += bb[d];
        }
        out[1500 + s * 4 + d] = ssum / fdn;
    } else if (tid == 16) {
        out[100 + s] = (float)c;
    } else if (tid == 17) {
        out[1400 + s] = (float)r;
    }
}

extern "C" void kernel_launch(void* const* d_in, const int* in_sizes, int n_in,
                              void* d_out, int out_size, void* d_ws, size_t ws_size,
                              hipStream_t stream) {
    const float* boxes = (const float*)d_in[1];
    const float* cls   = (const float*)d_in[2];
    const float* poses = (const float*)d_in[3];
    const float* conf  = (const float*)d_in[4];
    float* out = (float*)d_out;

    char* ws = (char*)d_ws;
    size_t off = 0;
    auto alloc = [&](size_t bytes) {
        void* p = ws + off;
        off += (bytes + 255) & ~(size_t)255;
        return p;
    };
    float4* boxesT   = (float4*)alloc(CN * sizeof(float4));
    float*  areaT    = (float*)alloc(CN * sizeof(float));
    float*  scoresT  = (float*)alloc(CN * sizeof(float));
    float*  confT    = (float*)alloc(CN * sizeof(float));
    int*    validList= (int*)alloc(CN * sizeof(int));
    float4* vBox     = (float4*)alloc(CN * sizeof(float4));
    float*  vArea    = (float*)alloc(CN * sizeof(float));
    float*  vConf    = (float*)alloc(CN * sizeof(float));
    int*    mVal     = (int*)alloc(64);
    int*    rep      = (int*)alloc(CN * sizeof(int));
    int*    surv     = (int*)alloc(CN * sizeof(int));
    int*    minRank  = (int*)alloc(CN * sizeof(int));
    int*    classCnt = (int*)alloc(64);

    k_prep<<<CN / 256, 256, 0, stream>>>(boxes, cls, conf, boxesT, areaT, scoresT, confT,
                                         surv, minRank, classCnt);
    k_validlist<<<NCLS, 1024, 0, stream>>>(scoresT, boxesT, areaT, confT,
                                           validList, vBox, vArea, vConf, mVal);
    k_repmat<<<NCLS * NTRI, 128, 0, stream>>>(vBox, vArea, mVal, minRank);
    k_repA<<<CN / 256, 256, 0, stream>>>(vBox, vArea, vConf, validList, mVal, minRank,
                                         rep, surv, classCnt);
    k_final<<<1 + MAX_DET, 1024, 0, stream>>>(boxesT, areaT, confT, scoresT, poses,
                                              rep, surv, classCnt, out);
}